// Round 18
// baseline (64.420 us; speedup 1.0000x reference)
//
#include <hip/hip_runtime.h>
#include <hip/hip_fp16.h>

#define B_   4
#define LQ_  256
#define LK_  512
#define DIN_ 512
#define H_   256
#define DV_  512

#define L2E 1.4426950408889634f   // log2(e)
// tanh(x) = 1 - 2/(e^{2x}+1);  e^{2(q+k)} = e^{2q} * e^{2k}.
// eq2/ek2 = 2^clamp(2x*L2E,±126): finite & nonzero -> no NaN; product
// over/underflow -> exact tanh saturation. Softmax without max-subtract:
// |score| <= ~38, 512*e^38 << fp32 max (verified r17, same absmax).

// =====================================================================
// Kernel 1: proj PARTIAL GEMM (r15 structure — best measured).
// 64r x 128h tiles, 256 thr, micro 8r x 4h. d-split: Q=4, K=8.
// grid 640; dead K tiles exit.
// =====================================================================
__global__ __launch_bounds__(256) void proj_partial_kernel(
    const float* __restrict__ Q, const float* __restrict__ K,
    const float* __restrict__ Wq, const float* __restrict__ Wk,
    const int* __restrict__ valid_lens,
    float* __restrict__ qpart, float* __restrict__ ekTpart) {
  __shared__ float xs[64][68];
  __shared__ float ws[64][132];

  const int blk = blockIdx.x;
  const bool isQ = blk < 128;
  int b, row0, h0, ds;
  if (isQ) {
    ds = blk & 3; h0 = ((blk >> 2) & 1) * 128;
    const int rt = blk >> 3;
    b = rt >> 2; row0 = (rt & 3) * 64;
  } else {
    const int u = blk - 128;
    ds = u & 7; h0 = ((u >> 3) & 1) * 128;
    const int rt = u >> 4;             // batch-interleaved
    b = rt & 3; row0 = (rt >> 2) * 64;
    if (row0 >= valid_lens[b]) return;
  }
  const int L = isQ ? LQ_ : LK_;
  const int dspan = isQ ? 128 : 64;
  const float* __restrict__ X  = (isQ ? Q : K) + ((size_t)(b * L + row0)) * DIN_ + ds * dspan;
  const float* __restrict__ Wb = (isQ ? Wq : Wk) + (size_t)(ds * dspan) * H_ + h0;

  const int t = threadIdx.x;
  const int hthr = t & 31;
  const int rthr = t >> 5;

  float acc[8][4];
#pragma unroll
  for (int r = 0; r < 8; ++r)
#pragma unroll
    for (int c = 0; c < 4; ++c) acc[r][c] = 0.f;

  for (int dd = 0; dd < dspan; dd += 64) {
    __syncthreads();
#pragma unroll
    for (int u = 0; u < 4; ++u) {
      const int f = t + 256 * u;
      const int r = f >> 4, c4 = (f & 15) << 2;
      *(float4*)&xs[r][c4] = *(const float4*)&X[(size_t)r * DIN_ + dd + c4];
    }
#pragma unroll
    for (int u = 0; u < 8; ++u) {
      const int f = t + 256 * u;
      const int k = f >> 5, c4 = (f & 31) << 2;
      *(float4*)&ws[k][c4] = *(const float4*)&Wb[(size_t)(dd + k) * H_ + c4];
    }
    __syncthreads();

    for (int k = 0; k < 64; k += 8) {
      float4 w4[8];
#pragma unroll
      for (int k8 = 0; k8 < 8; ++k8)
        w4[k8] = *(const float4*)&ws[k + k8][4 * hthr];
#pragma unroll
      for (int rr = 0; rr < 8; ++rr) {
        const float4 xa = *(const float4*)&xs[rthr * 8 + rr][k];
        const float4 xb = *(const float4*)&xs[rthr * 8 + rr][k + 4];
        const float xv[8] = {xa.x, xa.y, xa.z, xa.w, xb.x, xb.y, xb.z, xb.w};
#pragma unroll
        for (int k8 = 0; k8 < 8; ++k8) {
          acc[rr][0] = fmaf(xv[k8], w4[k8].x, acc[rr][0]);
          acc[rr][1] = fmaf(xv[k8], w4[k8].y, acc[rr][1]);
          acc[rr][2] = fmaf(xv[k8], w4[k8].z, acc[rr][2]);
          acc[rr][3] = fmaf(xv[k8], w4[k8].w, acc[rr][3]);
        }
      }
    }
  }

  if (isQ) {
    float* dst = qpart + (size_t)ds * (B_ * LQ_ * H_);
#pragma unroll
    for (int rr = 0; rr < 8; ++rr) {
      const int row = row0 + rthr * 8 + rr;
      float4 o = {acc[rr][0], acc[rr][1], acc[rr][2], acc[rr][3]};
      *(float4*)&dst[(size_t)(b * LQ_ + row) * H_ + h0 + 4 * hthr] = o;
    }
  } else {
    float* dst = ekTpart + (size_t)ds * (B_ * H_ * LK_);
#pragma unroll
    for (int c = 0; c < 4; ++c) {
      const int h = h0 + 4 * hthr + c;
      float* p = &dst[((size_t)b * H_ + h) * LK_ + row0 + rthr * 8];
      float4 lo = {acc[0][c], acc[1][c], acc[2][c], acc[3][c]};
      float4 hi = {acc[4][c], acc[5][c], acc[6][c], acc[7][c]};
      *(float4*)p = lo;
      *(float4*)(p + 4) = hi;
    }
  }
}

// =====================================================================
// Kernel 2: combine 8 ekT partials + squared exp  AND  V -> fp16 convert
// blocks [0,256): ek2; blocks [256,768): Vh. Block 0 also computes wsum.
// =====================================================================
__global__ __launch_bounds__(512) void combine_kernel(
    const float* __restrict__ ekTpart, const float* __restrict__ V,
    const float* __restrict__ wv,
    float* __restrict__ ek2, __half* __restrict__ Vh, float* __restrict__ wsum) {
  const int blk = blockIdx.x;
  const int t = threadIdx.x;
  if (blk < 256) {
    const int k4 = blk * 512 + t;
    const size_t KN4 = (size_t)B_ * H_ * LK_ / 4;
    const float4* src = (const float4*)ekTpart;
    float4 s = src[k4];
#pragma unroll
    for (int p = 1; p < 8; ++p) {
      const float4 v = src[p * KN4 + k4];
      s.x += v.x; s.y += v.y; s.z += v.z; s.w += v.w;
    }
    float4 o;
    o.x = exp2f(fminf(fmaxf(s.x * (2.f * L2E), -126.f), 126.f));
    o.y = exp2f(fminf(fmaxf(s.y * (2.f * L2E), -126.f), 126.f));
    o.z = exp2f(fminf(fmaxf(s.z * (2.f * L2E), -126.f), 126.f));
    o.w = exp2f(fminf(fmaxf(s.w * (2.f * L2E), -126.f), 126.f));
    ((float4*)ek2)[k4] = o;
    if (blk == 0 && t < 64) {
      float sw = wv[t] + wv[t + 64] + wv[t + 128] + wv[t + 192];
#pragma unroll
      for (int off = 32; off; off >>= 1) sw += __shfl_xor(sw, off);
      if (t == 0) *wsum = sw;
    }
  } else {
    const int q4 = (blk - 256) * 512 + t;      // 262144 float4 of V
    const float4 v = ((const float4*)V)[q4];
    ((__half2*)Vh)[2 * q4]     = __floats2half2_rn(v.x, v.y);
    ((__half2*)Vh)[2 * q4 + 1] = __floats2half2_rn(v.z, v.w);
  }
}

// =====================================================================
// Kernel 3: CHUNKED scores+exp. block = (b, 2 q-rows, 128-j chunk),
// 256 thr (jj = t&127, row = t>>7). Dead chunks exit -> live blocks
// proportional to vl, each with IDENTICAL work (perfect balance, ~4/CU).
// Writes e = exp2(score*L2E) (unnormalized) + per-chunk row sums.
// grid = 128 ip x 4 chunks x 4 b = 2048.
// =====================================================================
__global__ __launch_bounds__(256) void scores_exp_kernel(
    const float* __restrict__ qpart, const float* __restrict__ ek2,
    const float* __restrict__ wv, const float* __restrict__ wsum,
    const int* __restrict__ valid_lens,
    float* __restrict__ e_out, float* __restrict__ sums) {
  __shared__ float eqs[2][260];
  __shared__ float wvs[256];
  __shared__ float red[4];

  const int blk = blockIdx.x;
  const int b  = blk & 3;
  const int c  = (blk >> 2) & 3;
  const int ip = blk >> 4;
  const int i0 = ip * 2;
  const int vl = valid_lens[b];
  const int j0 = c * 128;
  if (j0 >= vl) return;                 // dead chunk (uniform, before barriers)
  const int t = threadIdx.x;
  const int jj = t & 127, row = t >> 7;

  // stage eq2 rows + wv
  const size_t QN = (size_t)B_ * LQ_ * H_;
#pragma unroll
  for (int u = 0; u < 2; ++u) {
    const int idx = t + 256 * u;
    const int i = idx >> 8, h = idx & 255;
    const size_t base = (size_t)(b * LQ_ + i0 + i) * H_ + h;
    const float v = qpart[base] + qpart[QN + base] +
                    qpart[2 * QN + base] + qpart[3 * QN + base];
    eqs[i][h] = exp2f(fminf(fmaxf(v * (2.f * L2E), -126.f), 126.f));
  }
  wvs[t] = wv[t];
  __syncthreads();
  const float Wsum = *wsum;

  const int j = j0 + jj;
  float eexp = 0.f;
  if (j < vl) {
    const float* __restrict__ kb = ek2 + (size_t)b * H_ * LK_ + j;
    float a = 0.f;
    for (int h = 0; h < H_; h += 16) {
      float kv[16];
#pragma unroll
      for (int u = 0; u < 16; ++u)
        kv[u] = kb[(size_t)(h + u) * LK_];       // 16 coalesced loads in flight
#pragma unroll
      for (int g = 0; g < 4; ++g) {
        const float4 w4 = *(const float4*)&wvs[h + 4 * g];
        const float4 q4 = *(const float4*)&eqs[row][h + 4 * g];  // wave-uniform
        const float ww[4] = {w4.x, w4.y, w4.z, w4.w};
        const float qq[4] = {q4.x, q4.y, q4.z, q4.w};
#pragma unroll
        for (int u = 0; u < 4; ++u)
          a = fmaf(ww[u], __builtin_amdgcn_rcpf(fmaf(qq[u], kv[4 * g + u], 1.f)), a);
      }
    }
    const float score = fmaf(-2.f, a, Wsum);
    eexp = exp2f(score * L2E);
    e_out[(size_t)(b * LQ_ + i0 + row) * LK_ + j] = eexp;   // coalesced
  }
  // per-chunk row sums (waves 0,1 -> row 0; waves 2,3 -> row 1)
  float s = eexp;
#pragma unroll
  for (int off = 32; off; off >>= 1) s += __shfl_xor(s, off);
  if ((t & 63) == 0) red[t >> 6] = s;
  __syncthreads();
  if (t == 0)   sums[(size_t)(b * LQ_ + i0) * 4 + c]     = red[0] + red[1];
  if (t == 128) sums[(size_t)(b * LQ_ + i0 + 1) * 4 + c] = red[2] + red[3];
}

// =====================================================================
// Kernel 4: AV with fp16 V. block = (b, 2 q-rows), 512 thr = DV cols,
// grid 512, batch-pair swizzle. Normalize by rcp(sum of live chunk-sums)
// at the END (only nc = ceil(vl/128) sums are valid — rest are poison).
// =====================================================================
__global__ __launch_bounds__(512) void av_kernel(
    const float* __restrict__ e_in, const float* __restrict__ sums,
    const __half* __restrict__ Vh, const int* __restrict__ valid_lens,
    float* __restrict__ out) {
  const int blk = blockIdx.x;
  const int b  = (blk & 3) ^ ((blk >> 8) & 1);
  const int i0 = (blk >> 2) * 2;
  const int vl = valid_lens[b];
  const int t = threadIdx.x;

  const int nc = min(4, (vl + 127) >> 7);
  float tot0 = 0.f, tot1 = 0.f;
  for (int c = 0; c < nc; ++c) {
    tot0 += sums[(size_t)(b * LQ_ + i0) * 4 + c];
    tot1 += sums[(size_t)(b * LQ_ + i0 + 1) * 4 + c];
  }
  const float inv0 = __builtin_amdgcn_rcpf(tot0);
  const float inv1 = __builtin_amdgcn_rcpf(tot1);

  const float* __restrict__ e0 = e_in + (size_t)(b * LQ_ + i0) * LK_;  // uniform
  const float* __restrict__ e1 = e0 + LK_;
  const __half* __restrict__ Vb = Vh + (size_t)b * LK_ * DV_ + t;

  float a0 = 0.f, a1 = 0.f;
  int j = 0;
  const int jv = vl & ~7;
  for (; j < jv; j += 8) {
    float v[8];
#pragma unroll
    for (int u = 0; u < 8; ++u)
      v[u] = __half2float(Vb[(size_t)(j + u) * DV_]);   // 8 loads in flight
#pragma unroll
    for (int u = 0; u < 8; ++u) {
      a0 = fmaf(e0[j + u], v[u], a0);     // e loads wave-uniform (scalar)
      a1 = fmaf(e1[j + u], v[u], a1);
    }
  }
  for (; j < vl; ++j) {
    const float v = __half2float(Vb[(size_t)j * DV_]);
    a0 = fmaf(e0[j], v, a0);
    a1 = fmaf(e1[j], v, a1);
  }
  out[(size_t)(b * LQ_ + i0) * DV_ + t]     = a0 * inv0;
  out[(size_t)(b * LQ_ + i0 + 1) * DV_ + t] = a1 * inv1;
}

extern "C" void kernel_launch(void* const* d_in, const int* in_sizes, int n_in,
                              void* d_out, int out_size, void* d_ws, size_t ws_size,
                              hipStream_t stream) {
  const float* queries    = (const float*)d_in[0];
  const float* keys       = (const float*)d_in[1];
  const float* values     = (const float*)d_in[2];
  const int*   valid_lens = (const int*)d_in[3];
  const float* Wq         = (const float*)d_in[4];
  const float* Wk         = (const float*)d_in[5];
  const float* wv         = (const float*)d_in[6];
  float* out = (float*)d_out;

  char* ws = (char*)d_ws;
  float*  qpart   = (float*)ws;                           // 4 x 1 MB @ 0
  float*  ekTpart = (float*)(ws + (size_t)( 4 << 20));    // 8 x 2 MB @ 4 MB
  float*  ek2     = (float*)(ws + (size_t)(20 << 20));    // 2 MB     @ 20 MB
  float*  e_buf   = (float*)(ws + (size_t)(22 << 20));    // 2 MB     @ 22 MB
  __half* Vh      = (__half*)(ws + (size_t)(24 << 20));   // 2 MB     @ 24 MB
  float*  sums    = (float*)(ws + (size_t)(26 << 20));    // 16 KB    @ 26 MB
  float*  wsum    = (float*)(ws + (size_t)(26 << 20) + 16384);

  proj_partial_kernel<<<640, 256, 0, stream>>>(
      queries, keys, Wq, Wk, valid_lens, qpart, ekTpart);
  combine_kernel<<<768, 512, 0, stream>>>(
      ekTpart, values, wv, ek2, Vh, wsum);
  scores_exp_kernel<<<2048, 256, 0, stream>>>(
      qpart, ek2, wv, wsum, valid_lens, e_buf, sums);
  av_kernel<<<512, 512, 0, stream>>>(
      e_buf, sums, Vh, valid_lens, out);
}

// Round 19
// 61.263 us; speedup vs baseline: 1.0515x; 1.0515x over previous
//
#include <hip/hip_runtime.h>
#include <hip/hip_fp16.h>

#define B_   4
#define LQ_  256
#define LK_  512
#define DIN_ 512
#define H_   256
#define DV_  512

#define L2E 1.4426950408889634f   // log2(e)
// tanh(x) = 1 - 2/(e^{2x}+1);  e^{2(q+k)} = e^{2q} * e^{2k}.
// eq2/ek2 = 2^clamp(2x*L2E,±126): finite & nonzero -> no NaN; product
// over/underflow -> exact tanh saturation. Softmax without max-subtract is
// safe: |score| <= ~38, 512*e^38 << fp32 max (verified r17/r18).

// =====================================================================
// Kernel 1: proj PARTIAL GEMM (r15 structure — best measured, frozen).
// 64r x 128h tiles, 256 thr, micro 8r x 4h. d-split: Q=4, K=8.
// grid 640; dead K tiles exit.
// =====================================================================
__global__ __launch_bounds__(256) void proj_partial_kernel(
    const float* __restrict__ Q, const float* __restrict__ K,
    const float* __restrict__ Wq, const float* __restrict__ Wk,
    const int* __restrict__ valid_lens,
    float* __restrict__ qpart, float* __restrict__ ekTpart) {
  __shared__ float xs[64][68];
  __shared__ float ws[64][132];

  const int blk = blockIdx.x;
  const bool isQ = blk < 128;
  int b, row0, h0, ds;
  if (isQ) {
    ds = blk & 3; h0 = ((blk >> 2) & 1) * 128;
    const int rt = blk >> 3;
    b = rt >> 2; row0 = (rt & 3) * 64;
  } else {
    const int u = blk - 128;
    ds = u & 7; h0 = ((u >> 3) & 1) * 128;
    const int rt = u >> 4;             // batch-interleaved
    b = rt & 3; row0 = (rt >> 2) * 64;
    if (row0 >= valid_lens[b]) return;
  }
  const int L = isQ ? LQ_ : LK_;
  const int dspan = isQ ? 128 : 64;
  const float* __restrict__ X  = (isQ ? Q : K) + ((size_t)(b * L + row0)) * DIN_ + ds * dspan;
  const float* __restrict__ Wb = (isQ ? Wq : Wk) + (size_t)(ds * dspan) * H_ + h0;

  const int t = threadIdx.x;
  const int hthr = t & 31;
  const int rthr = t >> 5;

  float acc[8][4];
#pragma unroll
  for (int r = 0; r < 8; ++r)
#pragma unroll
    for (int c = 0; c < 4; ++c) acc[r][c] = 0.f;

  for (int dd = 0; dd < dspan; dd += 64) {
    __syncthreads();
#pragma unroll
    for (int u = 0; u < 4; ++u) {
      const int f = t + 256 * u;
      const int r = f >> 4, c4 = (f & 15) << 2;
      *(float4*)&xs[r][c4] = *(const float4*)&X[(size_t)r * DIN_ + dd + c4];
    }
#pragma unroll
    for (int u = 0; u < 8; ++u) {
      const int f = t + 256 * u;
      const int k = f >> 5, c4 = (f & 31) << 2;
      *(float4*)&ws[k][c4] = *(const float4*)&Wb[(size_t)(dd + k) * H_ + c4];
    }
    __syncthreads();

    for (int k = 0; k < 64; k += 8) {
      float4 w4[8];
#pragma unroll
      for (int k8 = 0; k8 < 8; ++k8)
        w4[k8] = *(const float4*)&ws[k + k8][4 * hthr];
#pragma unroll
      for (int rr = 0; rr < 8; ++rr) {
        const float4 xa = *(const float4*)&xs[rthr * 8 + rr][k];
        const float4 xb = *(const float4*)&xs[rthr * 8 + rr][k + 4];
        const float xv[8] = {xa.x, xa.y, xa.z, xa.w, xb.x, xb.y, xb.z, xb.w};
#pragma unroll
        for (int k8 = 0; k8 < 8; ++k8) {
          acc[rr][0] = fmaf(xv[k8], w4[k8].x, acc[rr][0]);
          acc[rr][1] = fmaf(xv[k8], w4[k8].y, acc[rr][1]);
          acc[rr][2] = fmaf(xv[k8], w4[k8].z, acc[rr][2]);
          acc[rr][3] = fmaf(xv[k8], w4[k8].w, acc[rr][3]);
        }
      }
    }
  }

  if (isQ) {
    float* dst = qpart + (size_t)ds * (B_ * LQ_ * H_);
#pragma unroll
    for (int rr = 0; rr < 8; ++rr) {
      const int row = row0 + rthr * 8 + rr;
      float4 o = {acc[rr][0], acc[rr][1], acc[rr][2], acc[rr][3]};
      *(float4*)&dst[(size_t)(b * LQ_ + row) * H_ + h0 + 4 * hthr] = o;
    }
  } else {
    float* dst = ekTpart + (size_t)ds * (B_ * H_ * LK_);
#pragma unroll
    for (int c = 0; c < 4; ++c) {
      const int h = h0 + 4 * hthr + c;
      float* p = &dst[((size_t)b * H_ + h) * LK_ + row0 + rthr * 8];
      float4 lo = {acc[0][c], acc[1][c], acc[2][c], acc[3][c]};
      float4 hi = {acc[4][c], acc[5][c], acc[6][c], acc[7][c]};
      *(float4*)p = lo;
      *(float4*)(p + 4) = hi;
    }
  }
}

// =====================================================================
// Kernel 2: combine partials + squared exp for BOTH eq2 and ek2,
// plus V -> fp16. blocks: [0,128) eq2 | [128,384) ek2 | [384,896) Vh.
// Block 0 also computes wsum. All float4 elementwise.
// =====================================================================
__global__ __launch_bounds__(512) void combine_kernel(
    const float* __restrict__ qpart, const float* __restrict__ ekTpart,
    const float* __restrict__ V, const float* __restrict__ wv,
    float* __restrict__ eq2, float* __restrict__ ek2,
    __half* __restrict__ Vh, float* __restrict__ wsum) {
  const int blk = blockIdx.x;
  const int t = threadIdx.x;
  if (blk < 128) {
    const int k4 = blk * 512 + t;                 // 65536 f4
    const size_t QN4 = (size_t)B_ * LQ_ * H_ / 4;
    const float4* src = (const float4*)qpart;
    float4 s = src[k4];
#pragma unroll
    for (int p = 1; p < 4; ++p) {
      const float4 v = src[p * QN4 + k4];
      s.x += v.x; s.y += v.y; s.z += v.z; s.w += v.w;
    }
    float4 o;
    o.x = exp2f(fminf(fmaxf(s.x * (2.f * L2E), -126.f), 126.f));
    o.y = exp2f(fminf(fmaxf(s.y * (2.f * L2E), -126.f), 126.f));
    o.z = exp2f(fminf(fmaxf(s.z * (2.f * L2E), -126.f), 126.f));
    o.w = exp2f(fminf(fmaxf(s.w * (2.f * L2E), -126.f), 126.f));
    ((float4*)eq2)[k4] = o;
    if (blk == 0 && t < 64) {
      float sw = wv[t] + wv[t + 64] + wv[t + 128] + wv[t + 192];
#pragma unroll
      for (int off = 32; off; off >>= 1) sw += __shfl_xor(sw, off);
      if (t == 0) *wsum = sw;
    }
  } else if (blk < 384) {
    const int k4 = (blk - 128) * 512 + t;         // 131072 f4
    const size_t KN4 = (size_t)B_ * H_ * LK_ / 4;
    const float4* src = (const float4*)ekTpart;
    float4 s = src[k4];
#pragma unroll
    for (int p = 1; p < 8; ++p) {
      const float4 v = src[p * KN4 + k4];
      s.x += v.x; s.y += v.y; s.z += v.z; s.w += v.w;
    }
    float4 o;
    o.x = exp2f(fminf(fmaxf(s.x * (2.f * L2E), -126.f), 126.f));
    o.y = exp2f(fminf(fmaxf(s.y * (2.f * L2E), -126.f), 126.f));
    o.z = exp2f(fminf(fmaxf(s.z * (2.f * L2E), -126.f), 126.f));
    o.w = exp2f(fminf(fmaxf(s.w * (2.f * L2E), -126.f), 126.f));
    ((float4*)ek2)[k4] = o;
  } else {
    const int q4 = (blk - 384) * 512 + t;         // 262144 f4 of V
    const float4 v = ((const float4*)V)[q4];
    ((__half2*)Vh)[2 * q4]     = __floats2half2_rn(v.x, v.y);
    ((__half2*)Vh)[2 * q4 + 1] = __floats2half2_rn(v.z, v.w);
  }
}

// =====================================================================
// Kernel 3: CHUNKED scores+exp. block = (b, 4 q-rows, 128-j chunk),
// 256 thr: jj = t&127, rp = t>>7 (rows 2rp, 2rp+1). Dead chunks exit ->
// live blocks proportional to vl, each IDENTICAL work (~512 live, 2/CU).
// eq2 pre-computed (4KB coalesced stage). Writes e = exp2(score*L2E)
// (unnormalized) + per-(row,chunk) sums.
// grid = 64 ip x 4 c x 4 b = 1024 (b fastest).
// =====================================================================
__global__ __launch_bounds__(256) void scores_exp_kernel(
    const float* __restrict__ eq2, const float* __restrict__ ek2,
    const float* __restrict__ wv, const float* __restrict__ wsum,
    const int* __restrict__ valid_lens,
    float* __restrict__ e_out, float* __restrict__ sums) {
  __shared__ float eqs[4][260];
  __shared__ float wvs[256];
  __shared__ float red[4][2];

  const int blk = blockIdx.x;
  const int b  = blk & 3;
  const int c  = (blk >> 2) & 3;
  const int ip = blk >> 4;            // 0..63
  const int i0 = ip * 4;
  const int vl = valid_lens[b];
  const int j0 = c * 128;
  if (j0 >= vl) return;               // dead chunk (uniform, before barriers)
  const int t = threadIdx.x;
  const int jj = t & 127, rp = t >> 7;

  // stage eq2 rows (pre-exp'd): 4 x 256 = 256 f4, coalesced
  {
    const int r = t >> 6, c4 = (t & 63) << 2;
    *(float4*)&eqs[r][c4] =
        *(const float4*)&eq2[(size_t)(b * LQ_ + i0 + r) * H_ + c4];
  }
  wvs[t] = wv[t];
  __syncthreads();
  const float Wsum = *wsum;

  const int j = j0 + jj;
  float e0 = 0.f, e1 = 0.f;
  if (j < vl) {
    const float* __restrict__ kb = ek2 + (size_t)b * H_ * LK_ + j;
    float a0 = 0.f, a1 = 0.f;
    for (int h = 0; h < H_; h += 16) {
      float kv[16];
#pragma unroll
      for (int u = 0; u < 16; ++u)
        kv[u] = kb[(size_t)(h + u) * LK_];       // 16 coalesced loads in flight
#pragma unroll
      for (int g = 0; g < 4; ++g) {
        const float4 w4  = *(const float4*)&wvs[h + 4 * g];
        const float4 q0v = *(const float4*)&eqs[2 * rp][h + 4 * g];
        const float4 q1v = *(const float4*)&eqs[2 * rp + 1][h + 4 * g];
        const float ww[4] = {w4.x, w4.y, w4.z, w4.w};
        const float q0[4] = {q0v.x, q0v.y, q0v.z, q0v.w};
        const float q1[4] = {q1v.x, q1v.y, q1v.z, q1v.w};
#pragma unroll
        for (int u = 0; u < 4; ++u) {
          const float k2 = kv[4 * g + u];
          a0 = fmaf(ww[u], __builtin_amdgcn_rcpf(fmaf(q0[u], k2, 1.f)), a0);
          a1 = fmaf(ww[u], __builtin_amdgcn_rcpf(fmaf(q1[u], k2, 1.f)), a1);
        }
      }
    }
    e0 = exp2f(fmaf(-2.f, a0, Wsum) * L2E);
    e1 = exp2f(fmaf(-2.f, a1, Wsum) * L2E);
    e_out[(size_t)(b * LQ_ + i0 + 2 * rp) * LK_ + j]     = e0;   // coalesced
    e_out[(size_t)(b * LQ_ + i0 + 2 * rp + 1) * LK_ + j] = e1;
  }
  // per-(row, chunk) sums: waves 0,1 -> rows 0,1; waves 2,3 -> rows 2,3
  float s0 = e0, s1 = e1;
#pragma unroll
  for (int off = 32; off; off >>= 1) {
    s0 += __shfl_xor(s0, off);
    s1 += __shfl_xor(s1, off);
  }
  if ((t & 63) == 0) { red[t >> 6][0] = s0; red[t >> 6][1] = s1; }
  __syncthreads();
  if (t < 4) {
    const int w0 = (t >> 1) * 2, sel = t & 1;
    const float v = red[w0][sel] + red[w0 + 1][sel];
    sums[(size_t)(b * LQ_ + i0 + t) * 4 + c] = v;
  }
}

// =====================================================================
// Kernel 4: AV, fp16 V, R=4 rows/block -> grid 256 = exactly 1 block/CU.
// 512 thr = DV cols. e rows via uniform scalar loads; V stream halved by
// fp16 and amortized x4 rows. Normalize by rcp(sum of live chunk sums).
// =====================================================================
__global__ __launch_bounds__(512) void av_kernel(
    const float* __restrict__ e_in, const float* __restrict__ sums,
    const __half* __restrict__ Vh, const int* __restrict__ valid_lens,
    float* __restrict__ out) {
  const int blk = blockIdx.x;
  const int b  = blk & 3;
  const int i0 = (blk >> 2) * 4;
  const int vl = valid_lens[b];
  const int t = threadIdx.x;

  const int nc = min(4, (vl + 127) >> 7);
  float inv[4];
#pragma unroll
  for (int r = 0; r < 4; ++r) {
    float tot = 0.f;
    for (int c = 0; c < nc; ++c)
      tot += sums[(size_t)(b * LQ_ + i0 + r) * 4 + c];
    inv[r] = __builtin_amdgcn_rcpf(tot);
  }

  const float* __restrict__ e0 = e_in + (size_t)(b * LQ_ + i0) * LK_;  // uniform
  const float* __restrict__ e1 = e0 + LK_;
  const float* __restrict__ e2 = e1 + LK_;
  const float* __restrict__ e3 = e2 + LK_;
  const __half* __restrict__ Vb = Vh + (size_t)b * LK_ * DV_ + t;

  float a0 = 0.f, a1 = 0.f, a2 = 0.f, a3 = 0.f;
  int j = 0;
  const int jv = vl & ~7;
  for (; j < jv; j += 8) {
    float v[8];
#pragma unroll
    for (int u = 0; u < 8; ++u)
      v[u] = __half2float(Vb[(size_t)(j + u) * DV_]);   // 8 loads in flight
#pragma unroll
    for (int u = 0; u < 8; ++u) {
      a0 = fmaf(e0[j + u], v[u], a0);     // e via s_load (wave-uniform)
      a1 = fmaf(e1[j + u], v[u], a1);
      a2 = fmaf(e2[j + u], v[u], a2);
      a3 = fmaf(e3[j + u], v[u], a3);
    }
  }
  for (; j < vl; ++j) {
    const float v = __half2float(Vb[(size_t)j * DV_]);
    a0 = fmaf(e0[j], v, a0);
    a1 = fmaf(e1[j], v, a1);
    a2 = fmaf(e2[j], v, a2);
    a3 = fmaf(e3[j], v, a3);
  }
  out[(size_t)(b * LQ_ + i0) * DV_ + t]     = a0 * inv[0];
  out[(size_t)(b * LQ_ + i0 + 1) * DV_ + t] = a1 * inv[1];
  out[(size_t)(b * LQ_ + i0 + 2) * DV_ + t] = a2 * inv[2];
  out[(size_t)(b * LQ_ + i0 + 3) * DV_ + t] = a3 * inv[3];
}

extern "C" void kernel_launch(void* const* d_in, const int* in_sizes, int n_in,
                              void* d_out, int out_size, void* d_ws, size_t ws_size,
                              hipStream_t stream) {
  const float* queries    = (const float*)d_in[0];
  const float* keys       = (const float*)d_in[1];
  const float* values     = (const float*)d_in[2];
  const int*   valid_lens = (const int*)d_in[3];
  const float* Wq         = (const float*)d_in[4];
  const float* Wk         = (const float*)d_in[5];
  const float* wv         = (const float*)d_in[6];
  float* out = (float*)d_out;

  char* ws = (char*)d_ws;
  float*  qpart   = (float*)ws;                           // 4 x 1 MB @ 0
  float*  ekTpart = (float*)(ws + (size_t)( 4 << 20));    // 8 x 2 MB @ 4 MB
  float*  eq2     = (float*)(ws + (size_t)(20 << 20));    // 1 MB     @ 20 MB
  float*  ek2     = (float*)(ws + (size_t)(21 << 20));    // 2 MB     @ 21 MB
  float*  e_buf   = (float*)(ws + (size_t)(23 << 20));    // 2 MB     @ 23 MB
  __half* Vh      = (__half*)(ws + (size_t)(25 << 20));   // 2 MB     @ 25 MB
  float*  sums    = (float*)(ws + (size_t)(27 << 20));    // 16 KB    @ 27 MB
  float*  wsum    = (float*)(ws + (size_t)(27 << 20) + 16384);

  proj_partial_kernel<<<640, 256, 0, stream>>>(
      queries, keys, Wq, Wk, valid_lens, qpart, ekTpart);
  combine_kernel<<<896, 512, 0, stream>>>(
      qpart, ekTpart, values, wv, eq2, ek2, Vh, wsum);
  scores_exp_kernel<<<1024, 256, 0, stream>>>(
      eq2, ek2, wv, wsum, valid_lens, e_buf, sums);
  av_kernel<<<256, 512, 0, stream>>>(
      e_buf, sums, Vh, valid_lens, out);
}

// Round 20
// 55.510 us; speedup vs baseline: 1.1605x; 1.1037x over previous
//
#include <hip/hip_runtime.h>
#include <hip/hip_fp16.h>

#define B_   4
#define LQ_  256
#define LK_  512
#define DIN_ 512
#define H_   256
#define DV_  512

#define L2E 1.4426950408889634f   // log2(e)
// tanh(x) = 1 - 2/(e^{2x}+1);  e^{2(q+k)} = e^{2q} * e^{2k}.
// eq2/ek2 = 2^clamp(2x*L2E,±126): finite & nonzero -> no NaN; product
// over/underflow -> exact tanh saturation. Softmax without max-subtract is
// safe: |score| <= ~38, 512*e^38 << fp32 max (verified r17/r18/r19).

// =====================================================================
// Kernel 1: proj PARTIAL GEMM (r15 structure — best measured, frozen).
// 64r x 128h tiles, 256 thr, micro 8r x 4h. d-split: Q=4, K=8.
// grid 640; dead K tiles exit.
// =====================================================================
__global__ __launch_bounds__(256) void proj_partial_kernel(
    const float* __restrict__ Q, const float* __restrict__ K,
    const float* __restrict__ Wq, const float* __restrict__ Wk,
    const int* __restrict__ valid_lens,
    float* __restrict__ qpart, float* __restrict__ ekTpart) {
  __shared__ float xs[64][68];
  __shared__ float ws[64][132];

  const int blk = blockIdx.x;
  const bool isQ = blk < 128;
  int b, row0, h0, ds;
  if (isQ) {
    ds = blk & 3; h0 = ((blk >> 2) & 1) * 128;
    const int rt = blk >> 3;
    b = rt >> 2; row0 = (rt & 3) * 64;
  } else {
    const int u = blk - 128;
    ds = u & 7; h0 = ((u >> 3) & 1) * 128;
    const int rt = u >> 4;             // batch-interleaved
    b = rt & 3; row0 = (rt >> 2) * 64;
    if (row0 >= valid_lens[b]) return;
  }
  const int L = isQ ? LQ_ : LK_;
  const int dspan = isQ ? 128 : 64;
  const float* __restrict__ X  = (isQ ? Q : K) + ((size_t)(b * L + row0)) * DIN_ + ds * dspan;
  const float* __restrict__ Wb = (isQ ? Wq : Wk) + (size_t)(ds * dspan) * H_ + h0;

  const int t = threadIdx.x;
  const int hthr = t & 31;
  const int rthr = t >> 5;

  float acc[8][4];
#pragma unroll
  for (int r = 0; r < 8; ++r)
#pragma unroll
    for (int c = 0; c < 4; ++c) acc[r][c] = 0.f;

  for (int dd = 0; dd < dspan; dd += 64) {
    __syncthreads();
#pragma unroll
    for (int u = 0; u < 4; ++u) {
      const int f = t + 256 * u;
      const int r = f >> 4, c4 = (f & 15) << 2;
      *(float4*)&xs[r][c4] = *(const float4*)&X[(size_t)r * DIN_ + dd + c4];
    }
#pragma unroll
    for (int u = 0; u < 8; ++u) {
      const int f = t + 256 * u;
      const int k = f >> 5, c4 = (f & 31) << 2;
      *(float4*)&ws[k][c4] = *(const float4*)&Wb[(size_t)(dd + k) * H_ + c4];
    }
    __syncthreads();

    for (int k = 0; k < 64; k += 8) {
      float4 w4[8];
#pragma unroll
      for (int k8 = 0; k8 < 8; ++k8)
        w4[k8] = *(const float4*)&ws[k + k8][4 * hthr];
#pragma unroll
      for (int rr = 0; rr < 8; ++rr) {
        const float4 xa = *(const float4*)&xs[rthr * 8 + rr][k];
        const float4 xb = *(const float4*)&xs[rthr * 8 + rr][k + 4];
        const float xv[8] = {xa.x, xa.y, xa.z, xa.w, xb.x, xb.y, xb.z, xb.w};
#pragma unroll
        for (int k8 = 0; k8 < 8; ++k8) {
          acc[rr][0] = fmaf(xv[k8], w4[k8].x, acc[rr][0]);
          acc[rr][1] = fmaf(xv[k8], w4[k8].y, acc[rr][1]);
          acc[rr][2] = fmaf(xv[k8], w4[k8].z, acc[rr][2]);
          acc[rr][3] = fmaf(xv[k8], w4[k8].w, acc[rr][3]);
        }
      }
    }
  }

  if (isQ) {
    float* dst = qpart + (size_t)ds * (B_ * LQ_ * H_);
#pragma unroll
    for (int rr = 0; rr < 8; ++rr) {
      const int row = row0 + rthr * 8 + rr;
      float4 o = {acc[rr][0], acc[rr][1], acc[rr][2], acc[rr][3]};
      *(float4*)&dst[(size_t)(b * LQ_ + row) * H_ + h0 + 4 * hthr] = o;
    }
  } else {
    float* dst = ekTpart + (size_t)ds * (B_ * H_ * LK_);
#pragma unroll
    for (int c = 0; c < 4; ++c) {
      const int h = h0 + 4 * hthr + c;
      float* p = &dst[((size_t)b * H_ + h) * LK_ + row0 + rthr * 8];
      float4 lo = {acc[0][c], acc[1][c], acc[2][c], acc[3][c]};
      float4 hi = {acc[4][c], acc[5][c], acc[6][c], acc[7][c]};
      *(float4*)p = lo;
      *(float4*)(p + 4) = hi;
    }
  }
}

// =====================================================================
// Kernel 2: combine 8 ekT partials + squared exp  AND  V -> fp16.
// blocks [0,256): ek2 (+wsum in block 0); [256,768): Vh.
// =====================================================================
__global__ __launch_bounds__(512) void combine_kernel(
    const float* __restrict__ ekTpart, const float* __restrict__ V,
    const float* __restrict__ wv,
    float* __restrict__ ek2, __half* __restrict__ Vh, float* __restrict__ wsum) {
  const int blk = blockIdx.x;
  const int t = threadIdx.x;
  if (blk < 256) {
    const int k4 = blk * 512 + t;
    const size_t KN4 = (size_t)B_ * H_ * LK_ / 4;
    const float4* src = (const float4*)ekTpart;
    float4 s = src[k4];
#pragma unroll
    for (int p = 1; p < 8; ++p) {
      const float4 v = src[p * KN4 + k4];
      s.x += v.x; s.y += v.y; s.z += v.z; s.w += v.w;
    }
    float4 o;
    o.x = exp2f(fminf(fmaxf(s.x * (2.f * L2E), -126.f), 126.f));
    o.y = exp2f(fminf(fmaxf(s.y * (2.f * L2E), -126.f), 126.f));
    o.z = exp2f(fminf(fmaxf(s.z * (2.f * L2E), -126.f), 126.f));
    o.w = exp2f(fminf(fmaxf(s.w * (2.f * L2E), -126.f), 126.f));
    ((float4*)ek2)[k4] = o;
    if (blk == 0 && t < 64) {
      float sw = wv[t] + wv[t + 64] + wv[t + 128] + wv[t + 192];
#pragma unroll
      for (int off = 32; off; off >>= 1) sw += __shfl_xor(sw, off);
      if (t == 0) *wsum = sw;
    }
  } else {
    const int q4 = (blk - 256) * 512 + t;      // 262144 f4 of V
    const float4 v = ((const float4*)V)[q4];
    ((__half2*)Vh)[2 * q4]     = __floats2half2_rn(v.x, v.y);
    ((__half2*)Vh)[2 * q4 + 1] = __floats2half2_rn(v.z, v.w);
  }
}

// =====================================================================
// Kernel 3: FUSED eq+scores+softmax+AV. R=4 rows/block, 1024 thr,
// grid = 256 (1 block/CU, 16 waves = 4/SIMD). ek2 and V each streamed
// ONCE per 4 rows (3x less traffic than R=2). vl-adaptive phase 1
// (all threads busy); AV over full 512 j (e=0 masks; uniform work).
// =====================================================================
__global__ __launch_bounds__(1024) void fused_attn_kernel(
    const float* __restrict__ qpart, const float* __restrict__ ek2,
    const __half* __restrict__ Vh, const float* __restrict__ wv,
    const float* __restrict__ wsum, const int* __restrict__ valid_lens,
    float* __restrict__ out) {
  __shared__ float eqs[4][260];      // 4.2 KB
  __shared__ float wvs[256];         // 1 KB
  __shared__ float phbuf[2 * 4 * 512];   // 16 KB (aliased A/B)
  __shared__ float e2s[512][4];      // 8 KB  (e per j, float4 across rows)
  __shared__ float avp[2][512][4];   // 16 KB (AV partials per j-half)
  __shared__ float red[8][4];
  __shared__ float tots[4];

  const int blk = blockIdx.x;
  const int b  = blk & 3;
  const int i0 = (blk >> 2) * 4;
  const int vl = valid_lens[b];
  const int t = threadIdx.x;
  const float Wsum = *wsum;

  // ---- phase 0: eq2 rows (4 x 256 = 1024 elements, one per thread) ----
  const size_t QN = (size_t)B_ * LQ_ * H_;
  {
    const int r = t >> 8, h = t & 255;
    const size_t base = (size_t)(b * LQ_ + i0 + r) * H_ + h;
    const float v = qpart[base] + qpart[QN + base] +
                    qpart[2 * QN + base] + qpart[3 * QN + base];
    eqs[r][h] = exp2f(fminf(fmaxf(v * (2.f * L2E), -126.f), 126.f));
    if (r == 0) wvs[h] = wv[h];
  }
  __syncthreads();

  // ---- phase 1: scores, vl-adaptive, all threads busy ----
#define PHA(hh, r, j) phbuf[(((hh) << 2) + (r)) * 512 + (j)]
#define PHB(hq, r, j) phbuf[(((hq) << 2) + (r)) * 256 + (j)]
  if (vl > 256) {
    const int j = t & 511, hh = t >> 9;   // 2 h-halves x 128
    if (j < vl) {
      const float* __restrict__ kb = ek2 + (size_t)b * H_ * LK_ + j;
      const int hb = hh * 128;
      float a[4] = {0.f, 0.f, 0.f, 0.f};
      for (int h2 = 0; h2 < 128; h2 += 16) {
        const int h = hb + h2;
        float kv[16];
#pragma unroll
        for (int u = 0; u < 16; ++u)
          kv[u] = kb[(size_t)(h + u) * LK_];     // 16 coalesced loads in flight
#pragma unroll
        for (int g = 0; g < 4; ++g) {
          const float4 w4 = *(const float4*)&wvs[h + 4 * g];
          const float ww[4] = {w4.x, w4.y, w4.z, w4.w};
#pragma unroll
          for (int r = 0; r < 4; ++r) {
            const float4 q4 = *(const float4*)&eqs[r][h + 4 * g];
            const float qq[4] = {q4.x, q4.y, q4.z, q4.w};
#pragma unroll
            for (int u = 0; u < 4; ++u)
              a[r] = fmaf(ww[u],
                  __builtin_amdgcn_rcpf(fmaf(qq[u], kv[4 * g + u], 1.f)), a[r]);
          }
        }
      }
#pragma unroll
      for (int r = 0; r < 4; ++r) PHA(hh, r, j) = a[r];
    }
  } else {
    const int j = t & 255, hq = t >> 8;   // 4 h-quarters x 64
    if (j < vl) {
      const float* __restrict__ kb = ek2 + (size_t)b * H_ * LK_ + j;
      const int hb = hq * 64;
      float a[4] = {0.f, 0.f, 0.f, 0.f};
      for (int h2 = 0; h2 < 64; h2 += 16) {
        const int h = hb + h2;
        float kv[16];
#pragma unroll
        for (int u = 0; u < 16; ++u)
          kv[u] = kb[(size_t)(h + u) * LK_];
#pragma unroll
        for (int g = 0; g < 4; ++g) {
          const float4 w4 = *(const float4*)&wvs[h + 4 * g];
          const float ww[4] = {w4.x, w4.y, w4.z, w4.w};
#pragma unroll
          for (int r = 0; r < 4; ++r) {
            const float4 q4 = *(const float4*)&eqs[r][h + 4 * g];
            const float qq[4] = {q4.x, q4.y, q4.z, q4.w};
#pragma unroll
            for (int u = 0; u < 4; ++u)
              a[r] = fmaf(ww[u],
                  __builtin_amdgcn_rcpf(fmaf(qq[u], kv[4 * g + u], 1.f)), a[r]);
          }
        }
      }
#pragma unroll
      for (int r = 0; r < 4; ++r) PHB(hq, r, j) = a[r];
    }
  }
  __syncthreads();

  // ---- phase 2: e = exp(score) (thread j < 512), wave-reduce sums ----
  if (t < 512) {
    const int j = t;
    float er[4] = {0.f, 0.f, 0.f, 0.f};
    if (j < vl) {
      if (vl > 256) {
#pragma unroll
        for (int r = 0; r < 4; ++r) {
          const float a = PHA(0, r, j) + PHA(1, r, j);
          er[r] = exp2f(fmaf(-2.f, a, Wsum) * L2E);
        }
      } else {
#pragma unroll
        for (int r = 0; r < 4; ++r) {
          const float a = PHB(0, r, j) + PHB(1, r, j) + PHB(2, r, j) + PHB(3, r, j);
          er[r] = exp2f(fmaf(-2.f, a, Wsum) * L2E);
        }
      }
    }
    *(float4*)&e2s[j][0] = *(float4*)er;
    float s0 = er[0], s1 = er[1], s2 = er[2], s3 = er[3];
#pragma unroll
    for (int off = 32; off; off >>= 1) {
      s0 += __shfl_xor(s0, off); s1 += __shfl_xor(s1, off);
      s2 += __shfl_xor(s2, off); s3 += __shfl_xor(s3, off);
    }
    if ((t & 63) == 0) {
      const int w = t >> 6;
      red[w][0] = s0; red[w][1] = s1; red[w][2] = s2; red[w][3] = s3;
    }
  }
  __syncthreads();
  if (t < 4) {
    float s = 0.f;
#pragma unroll
    for (int w = 0; w < 8; ++w) s += red[w][t];
    tots[t] = s;
  }

  // ---- phase 3: AV over full 512 j (e=0 masks), fp16 V ----
  {
    const int col = t & 511, jh = t >> 9;
    const __half* __restrict__ Vb = Vh + (size_t)b * LK_ * DV_ + col;
    float a0 = 0.f, a1 = 0.f, a2 = 0.f, a3 = 0.f;
    const int jbase = jh * 256;
    for (int j = jbase; j < jbase + 256; j += 8) {
      float v[8];
#pragma unroll
      for (int u = 0; u < 8; ++u)
        v[u] = __half2float(Vb[(size_t)(j + u) * DV_]);   // 8 loads in flight
#pragma unroll
      for (int u = 0; u < 8; ++u) {
        const float4 ee = *(const float4*)&e2s[j + u][0];  // b128 broadcast
        a0 = fmaf(ee.x, v[u], a0); a1 = fmaf(ee.y, v[u], a1);
        a2 = fmaf(ee.z, v[u], a2); a3 = fmaf(ee.w, v[u], a3);
      }
    }
    float o[4] = {a0, a1, a2, a3};
    *(float4*)&avp[jh][col][0] = *(float4*)o;
  }
  __syncthreads();
  if (t < 512) {
    const float4 x0 = *(const float4*)&avp[0][t][0];
    const float4 x1 = *(const float4*)&avp[1][t][0];
    const float i0r = __builtin_amdgcn_rcpf(tots[0]);
    const float i1r = __builtin_amdgcn_rcpf(tots[1]);
    const float i2r = __builtin_amdgcn_rcpf(tots[2]);
    const float i3r = __builtin_amdgcn_rcpf(tots[3]);
    out[(size_t)(b * LQ_ + i0) * DV_ + t]     = (x0.x + x1.x) * i0r;
    out[(size_t)(b * LQ_ + i0 + 1) * DV_ + t] = (x0.y + x1.y) * i1r;
    out[(size_t)(b * LQ_ + i0 + 2) * DV_ + t] = (x0.z + x1.z) * i2r;
    out[(size_t)(b * LQ_ + i0 + 3) * DV_ + t] = (x0.w + x1.w) * i3r;
  }
}

extern "C" void kernel_launch(void* const* d_in, const int* in_sizes, int n_in,
                              void* d_out, int out_size, void* d_ws, size_t ws_size,
                              hipStream_t stream) {
  const float* queries    = (const float*)d_in[0];
  const float* keys       = (const float*)d_in[1];
  const float* values     = (const float*)d_in[2];
  const int*   valid_lens = (const int*)d_in[3];
  const float* Wq         = (const float*)d_in[4];
  const float* Wk         = (const float*)d_in[5];
  const float* wv         = (const float*)d_in[6];
  float* out = (float*)d_out;

  char* ws = (char*)d_ws;
  float*  qpart   = (float*)ws;                           // 4 x 1 MB @ 0
  float*  ekTpart = (float*)(ws + (size_t)( 4 << 20));    // 8 x 2 MB @ 4 MB
  float*  ek2     = (float*)(ws + (size_t)(20 << 20));    // 2 MB     @ 20 MB
  __half* Vh      = (__half*)(ws + (size_t)(22 << 20));   // 2 MB     @ 22 MB
  float*  wsum    = (float*)(ws + (size_t)(24 << 20));    // 4 B      @ 24 MB

  proj_partial_kernel<<<640, 256, 0, stream>>>(
      queries, keys, Wq, Wk, valid_lens, qpart, ekTpart);
  combine_kernel<<<768, 512, 0, stream>>>(
      ekTpart, values, wv, ek2, Vh, wsum);
  fused_attn_kernel<<<256, 1024, 0, stream>>>(
      qpart, ek2, Vh, wv, wsum, valid_lens, out);
}